// Round 16
// baseline (450.430 us; speedup 1.0000x reference)
//
#include <hip/hip_runtime.h>

typedef __bf16 bf16x8 __attribute__((ext_vector_type(8)));
typedef float  f32x4  __attribute__((ext_vector_type(4)));
typedef float  fvec4  __attribute__((ext_vector_type(4)));

#define NSPEC 8
#define NB    65536
#define NF    256

// ---------------------------------------------------------------------------
// Prologue: W[l][s][in][out] f32  ->  WT[l][s][out][in] bf16   (3 MB in d_ws)
// ---------------------------------------------------------------------------
__global__ __launch_bounds__(256) void wconv_kernel(
    const float* __restrict__ W1, const float* __restrict__ W2,
    const float* __restrict__ W3, __bf16* __restrict__ WT)
{
    __shared__ float tile[32][33];
    int bid = blockIdx.x;
    int l   = bid >> 9;
    int rem = bid & 511;
    int s   = rem >> 6;
    int tt  = rem & 63;
    int ti  = tt >> 3, tj = tt & 7;
    const float* W   = (l == 0) ? W1 : (l == 1) ? W2 : W3;
    const float* ibs = W + (size_t)s * 65536;
    int c  = threadIdx.x & 31;
    int r0 = threadIdx.x >> 5;
#pragma unroll
    for (int k = 0; k < 4; ++k) {
        int r = r0 + k * 8;
        tile[r][c] = ibs[(ti * 32 + r) * 256 + tj * 32 + c];
    }
    __syncthreads();
    __bf16* obs = WT + ((size_t)(l * 8 + s)) * 65536;
#pragma unroll
    for (int k = 0; k < 4; ++k) {
        int r = r0 + k * 8;
        obs[(tj * 32 + r) * 256 + ti * 32 + c] = (__bf16)tile[c][r];
    }
}

// full barrier WITHOUT vmcnt drain: in-flight weight loads survive.
#define BAR()                                                            \
    do {                                                                 \
        __builtin_amdgcn_sched_barrier(0);                               \
        asm volatile("s_waitcnt lgkmcnt(0)" ::: "memory");               \
        __builtin_amdgcn_s_barrier();                                    \
        __builtin_amdgcn_sched_barrier(0);                               \
    } while (0)

// ---------------------------------------------------------------------------
// Fused MLP, species-split. WEIGHTS GLOBAL->REGISTERS (depth-3 ring, no LDS
// transit): removes af ds_reads + gll LDS writes -> LDS traffic 2.6x down
// (the measured gate: 8 schedule variants all pinned at MfmaUtil ~25%).
// All loads compiler-tracked (exact per-operand waitcnt); sched_barrier(0)
// step fences prevent sinking. LDS = 32KB act (in-place) + 3KB bias.
// ---------------------------------------------------------------------------
__global__ __launch_bounds__(256, 2) void mlp_kernel(
    const float* __restrict__ bIn, const float* __restrict__ b1,
    const float* __restrict__ b2,  const float* __restrict__ b3,
    const float* __restrict__ W4,  const float* __restrict__ b4,
    const __bf16* __restrict__ WT, float* __restrict__ P)
{
    __shared__ __align__(16) __bf16 act[64 * 256];   // 32 KB act, in-place
    __shared__ __align__(16) float  bias_lds[3][256];// 3 KB biases

    const int t    = threadIdx.x;
    const int lane = t & 63;
    const int wave = t >> 6;          // 0..3, owns v-range [wave*64, wave*64+64)
    const int l15  = lane & 15;
    const int g    = lane >> 4;       // 0..3
    const int wv   = wave * 64;
    const int s    = blockIdx.x >> 10;
    const int row0 = (blockIdx.x & 1023) * 64;
    const int swzB = l15 << 4;
    char* const pA = (char*)act;

    const char* const wt0 = (const char*)(WT + ((size_t)(0 * 8 + s) << 16));
    const char* const wt1 = (const char*)(WT + ((size_t)(1 * 8 + s) << 16));
    const char* const wt2 = (const char*)(WT + ((size_t)(2 * 8 + s) << 16));

// load the 4 A-fragments of chunk c (k-slice c&7) straight into registers
#define WLOAD(DST, c)                                                    \
    do {                                                                 \
        const char* wb_ = ((c) < 8) ? wt0 : ((c) < 16) ? wt1 : wt2;      \
        _Pragma("unroll")                                                \
        for (int m_ = 0; m_ < 4; ++m_)                                   \
            DST[m_] = *(const bf16x8*)(wb_ + (wv + m_ * 16 + l15) * 512  \
                                       + ((c) & 7) * 64 + g * 16);       \
    } while (0)

#define READ_B(BF, kslice)                                               \
    do {                                                                 \
        _Pragma("unroll")                                                \
        for (int n_ = 0; n_ < 4; ++n_)                                   \
            BF[n_] = *(const bf16x8*)(pA + (n_ * 16 + l15) * 512 +       \
                                      (((kslice) * 64 + g * 16) ^ swzB));\
    } while (0)

#define MFMA_SET(AF, BF)                                                 \
    do {                                                                 \
        __builtin_amdgcn_s_setprio(1);                                   \
        _Pragma("unroll")                                                \
        for (int m_ = 0; m_ < 4; ++m_)                                   \
            _Pragma("unroll")                                            \
            for (int n_ = 0; n_ < 4; ++n_)                               \
                acc[m_][n_] = __builtin_amdgcn_mfma_f32_16x16x32_bf16(   \
                    AF[m_], BF[n_], acc[m_][n_], 0, 0, 0);               \
        __builtin_amdgcn_s_setprio(0);                                   \
    } while (0)

    // ---- stage biases into LDS (one-time)
    if (t < 192) {
        int bl  = t >> 6;              // 0..2
        int off = (t & 63) * 4;
        const float* bp = (bl == 0 ? b1 : bl == 1 ? b2 : b3) + s * 256 + off;
        *(fvec4*)&bias_lds[bl][off] = *(const fvec4*)bp;
    }

    // ---- stage b[s][row0..row0+63][:] fp32 -> bf16 into act (swizzled)
    const float* src = bIn + ((size_t)s * NB + row0) * NF;
#pragma unroll
    for (int it = 0; it < 16; ++it) {
        int flat = it * 1024 + t * 4;
        int r = flat >> 8;
        int f = flat & 255;
        fvec4 v = __builtin_nontemporal_load((const fvec4*)(src + flat));
        union { __bf16 h[4]; unsigned long long q; } pk;
        pk.h[0] = (__bf16)v[0]; pk.h[1] = (__bf16)v[1];
        pk.h[2] = (__bf16)v[2]; pk.h[3] = (__bf16)v[3];
        *(unsigned long long*)(pA + r * 512 + ((f * 2) ^ ((r & 15) << 4))) = pk.q;
    }
    __builtin_amdgcn_sched_barrier(0);

    // ---- prime the weight register ring (3 chunks in flight)
    bf16x8 wreg[3][4];
    WLOAD(wreg[0], 0);
    WLOAD(wreg[1], 1);
    WLOAD(wreg[2], 2);
    BAR();   // act + bias staged; weight loads fly over (no vmcnt drain)

#pragma unroll
    for (int l = 0; l < 3; ++l) {
        f32x4 acc[4][4];
#pragma unroll
        for (int m = 0; m < 4; ++m)
#pragma unroll
            for (int n = 0; n < 4; ++n)
                acc[m][n] = (f32x4){0.f, 0.f, 0.f, 0.f};

        bf16x8 bfX[4], bfY[4];
        READ_B(bfX, 0);

#pragma unroll
        for (int ks = 0; ks < 8; ++ks) {
            const int c = l * 8 + ks;          // weight chunk for this step
            if (ks < 7) {
                if ((ks & 1) == 0) READ_B(bfY, ks + 1);
                else               READ_B(bfX, ks + 1);
            }
            // compiler inserts exact vmcnt for wreg[c%3] / lgkmcnt for bf set
            if ((ks & 1) == 0) MFMA_SET(wreg[c % 3], bfX);
            else               MFMA_SET(wreg[c % 3], bfY);
            // refill the set just consumed (WAR safe: in-order issue)
            if (c + 3 <= 23) WLOAD(wreg[(c + 3) % 3], c + 3);
            __builtin_amdgcn_sched_barrier(0);
        }

        BAR();   // all act reads complete before in-place update

        // epilogue: +bias (from LDS), leaky, cvt bf16, packed 8B write
#pragma unroll
        for (int m = 0; m < 4; ++m) {
            fvec4 bq = *(const fvec4*)&bias_lds[l][wv + m * 16 + g * 4];
            int vbyte = (wv + m * 16 + g * 4) * 2;
#pragma unroll
            for (int n = 0; n < 4; ++n) {
                union { __bf16 h[4]; unsigned long long q; } pk;
#pragma unroll
                for (int j = 0; j < 4; ++j) {
                    float x = acc[m][n][j] + bq[j];
                    x = (x >= 0.f) ? x : 0.1f * x;
                    pk.h[j] = (__bf16)x;
                }
                *(unsigned long long*)(pA + (n * 16 + l15) * 512 + (vbyte ^ swzB)) = pk.q;
            }
        }
        BAR();
    }

    // ---- layer 4: A_s[row] = dot(act3[row], w4[s]) + b4[s] -> partial P
    const int r4   = t >> 2;
    const int u0   = (t & 3) * 64;
    const int swz4 = (r4 & 15) << 4;
    const float* w4s = W4 + s * 256 + u0;
    float part = 0.f;
#pragma unroll
    for (int i = 0; i < 8; ++i) {
        bf16x8 x = *(const bf16x8*)(pA + r4 * 512 + (((u0 + i * 8) * 2) ^ swz4));
        fvec4 wlo = *(const fvec4*)(w4s + i * 8);
        fvec4 whi = *(const fvec4*)(w4s + i * 8 + 4);
        part += (float)x[0] * wlo[0] + (float)x[1] * wlo[1] +
                (float)x[2] * wlo[2] + (float)x[3] * wlo[3] +
                (float)x[4] * whi[0] + (float)x[5] * whi[1] +
                (float)x[6] * whi[2] + (float)x[7] * whi[3];
    }
    part += __shfl_xor(part, 1);
    part += __shfl_xor(part, 2);
    if ((t & 3) == 0) P[(size_t)s * NB + row0 + r4] = part + b4[s];
}

// ---------------------------------------------------------------------------
// Final: out[i] = sigmoid(sum_s P[s][i])
// ---------------------------------------------------------------------------
__global__ __launch_bounds__(256) void reduce_kernel(
    const float* __restrict__ P, float* __restrict__ out)
{
    int i = blockIdx.x * 256 + threadIdx.x;
    float a = 0.f;
#pragma unroll
    for (int sp = 0; sp < NSPEC; ++sp) a += P[(size_t)sp * NB + i];
    out[i] = 1.f / (1.f + __expf(-a));
}

extern "C" void kernel_launch(void* const* d_in, const int* in_sizes, int n_in,
                              void* d_out, int out_size, void* d_ws, size_t ws_size,
                              hipStream_t stream)
{
    const float* bIn = (const float*)d_in[0];
    const float* W1  = (const float*)d_in[1];
    const float* b1  = (const float*)d_in[2];
    const float* W2  = (const float*)d_in[3];
    const float* b2  = (const float*)d_in[4];
    const float* W3  = (const float*)d_in[5];
    const float* b3  = (const float*)d_in[6];
    const float* W4  = (const float*)d_in[7];
    const float* b4  = (const float*)d_in[8];
    __bf16* WT = (__bf16*)d_ws;                       // 3 MB
    float*  P  = (float*)((char*)d_ws + (3u << 20));  // 2 MB partials

    wconv_kernel<<<1536, 256, 0, stream>>>(W1, W2, W3, WT);
    mlp_kernel<<<8192, 256, 0, stream>>>(bIn, b1, b2, b3, W4, b4, WT, P);
    reduce_kernel<<<NB / 256, 256, 0, stream>>>(P, (float*)d_out);
}